// Round 15
// baseline (521.105 us; speedup 1.0000x reference)
//
#include <hip/hip_runtime.h>
#include <hip/hip_bf16.h>

#define B_SZ 16
#define IN_C 64
#define OUT_C 64
#define STYLE_DIM 512
#define HW 16384          // 128*128
#define EPS 1e-8f

// ---------------------------------------------------------------------------
// Kernel 1: modulated+demodulated weight, stored TRANSPOSED: WT[b][i][o].
// 16 blocks x 256 threads. (Identical math to R13's verified version.)
// ---------------------------------------------------------------------------
__global__ __launch_bounds__(256) void modw_kernel(
    const float* __restrict__ style,   // (B, STYLE_DIM)
    const float* __restrict__ weight,  // (OUT_C, IN_C)
    const float* __restrict__ geo_w,   // (IN_C, STYLE_DIM)
    const float* __restrict__ geo_b,   // (IN_C)
    float* __restrict__ WT)            // (B, IN_C, OUT_C)
{
    const int b   = blockIdx.x;
    const int tid = threadIdx.x;
    __shared__ float smod[IN_C];

    {   // smod[i] = dot(style[b], geo_w[i]) + geo_b[i] + 1
        const int i    = tid >> 2;
        const int part = tid & 3;
        const float4* st4 = reinterpret_cast<const float4*>(style + b * STYLE_DIM + part * 128);
        const float4* gw4 = reinterpret_cast<const float4*>(geo_w + i * STYLE_DIM + part * 128);
        float s = 0.0f;
        #pragma unroll
        for (int k = 0; k < 32; ++k) {
            const float4 a = st4[k];
            const float4 g = gw4[k];
            s = fmaf(a.x, g.x, s); s = fmaf(a.y, g.y, s);
            s = fmaf(a.z, g.z, s); s = fmaf(a.w, g.w, s);
        }
        s += __shfl_xor(s, 1);
        s += __shfl_xor(s, 2);
        if (part == 0) smod[i] = s + geo_b[i] + 1.0f;
    }
    __syncthreads();

    {   // demod + transposed store; 4 threads per o
        const int o    = tid >> 2;
        const int part = tid & 3;
        const float* wr = weight + o * IN_C + part * 16;
        const float* sm = smod + part * 16;
        float wv[16];
        float d = 0.0f;
        #pragma unroll
        for (int k = 0; k < 16; ++k) {
            wv[k] = wr[k] * sm[k];
            d = fmaf(wv[k], wv[k], d);
        }
        d += __shfl_xor(d, 1);
        d += __shfl_xor(d, 2);
        d = rsqrtf(d + EPS);
        #pragma unroll
        for (int k = 0; k < 16; ++k)
            WT[(b << 12) + (part * 16 + k) * OUT_C + o] = wv[k] * d;
    }
}

// ---------------------------------------------------------------------------
// Kernel 2 (hot): out[b][o][hw] = sum_i WT[b][i][o] * x[b][i][hw] + bias[o]
//
// R13 established the right structure (no LDS, no barriers, scalar-pipe W
// via wave-uniform og, VGPR=40, occupancy 51%, memory-bound). Its residual
// losses were narrow accesses: float2 loads/stores showed 3.5x FETCH and
// 3.75x WRITE inflation vs R12's exact-traffic float4 accesses, and only
// ~16KB/CU in flight (2.17 TB/s). This version widens to float4 everywhere:
// lane = 4 hw, wave = 16 o x 256 hw, block = 4 waves = 64 o x 256 hw.
// acc[16] float4 = 64 VGPR; (256,4) -> 16 waves/CU, >=32KB/CU in flight.
// W loads: wr[o] off a readfirstlane-uniform base -> s_load (SMEM pipe),
// one s_load_dwordx16 per i-iteration, no VGPR cost, no LDS, no barrier.
// ---------------------------------------------------------------------------
__global__ __launch_bounds__(256, 4) void conv_kernel(
    const float* __restrict__ x,     // (B, IN_C, HW)
    const float* __restrict__ WT,    // (B, IN_C, OUT_C)
    const float* __restrict__ bias,  // (OUT_C)
    float* __restrict__ out)         // (B, OUT_C, HW)
{
    const int tid  = threadIdx.x;
    const int b    = blockIdx.x >> 6;             // 64 tiles per sample
    const int hwt  = (blockIdx.x & 63) << 8;      // 256 hw per block
    const int lane = tid & 63;
    int og = (tid >> 6) << 4;                     // 0,16,32,48 (wave-uniform)
    og = __builtin_amdgcn_readfirstlane(og);

    const float* wb = WT + (b << 12) + og;        // + i*64 + o (uniform)
    const float* xb = x + (size_t)(b << 6) * HW + hwt + (lane << 2);

    float4 acc[16];
    #pragma unroll
    for (int o = 0; o < 16; ++o) acc[o] = make_float4(0.0f, 0.0f, 0.0f, 0.0f);

    // rolling depth-2 prefetch of x (1 KB/wave per load instruction)
    float4 x0 = *reinterpret_cast<const float4*>(xb);
    float4 x1 = *reinterpret_cast<const float4*>(xb + HW);

    #pragma unroll
    for (int i = 0; i < IN_C; ++i) {
        float4 xn = x1;
        if (i + 2 < IN_C)
            xn = *reinterpret_cast<const float4*>(xb + (size_t)(i + 2) * HW);
        const float* wr = wb + (i << 6);
        #pragma unroll
        for (int o = 0; o < 16; ++o) {
            const float w = wr[o];                // uniform -> s_load
            acc[o].x = fmaf(w, x0.x, acc[o].x);
            acc[o].y = fmaf(w, x0.y, acc[o].y);
            acc[o].z = fmaf(w, x0.z, acc[o].z);
            acc[o].w = fmaf(w, x0.w, acc[o].w);
        }
        x0 = x1; x1 = xn;
    }

    float* ob = out + (size_t)((b << 6) + og) * HW + hwt + (lane << 2);
    #pragma unroll
    for (int o = 0; o < 16; ++o) {
        const float bv = bias[og + o];            // uniform -> s_load
        const float4 r = make_float4(acc[o].x + bv, acc[o].y + bv,
                                     acc[o].z + bv, acc[o].w + bv);
        *reinterpret_cast<float4*>(ob + (size_t)o * HW) = r;   // 1 KB/wave
    }
}

extern "C" void kernel_launch(void* const* d_in, const int* in_sizes, int n_in,
                              void* d_out, int out_size, void* d_ws, size_t ws_size,
                              hipStream_t stream) {
    const float* x      = (const float*)d_in[0];  // (16,64,128,128)
    const float* style  = (const float*)d_in[1];  // (16,512)
    const float* weight = (const float*)d_in[2];  // (1,64,64,1,1)
    const float* bias   = (const float*)d_in[3];  // (1,64)
    const float* geo_w  = (const float*)d_in[4];  // (64,512)
    const float* geo_b  = (const float*)d_in[5];  // (64)
    float* out = (float*)d_out;
    float* WT  = (float*)d_ws;                    // 16*64*64*4 = 64 KB

    modw_kernel<<<B_SZ, 256, 0, stream>>>(style, weight, geo_w, geo_b, WT);
    conv_kernel<<<B_SZ * (HW / 256), 256, 0, stream>>>(x, WT, bias, out);
}